// Round 1
// baseline (1410.343 us; speedup 1.0000x reference)
//
#include <hip/hip_runtime.h>

#define D 300
#define BLOCK_MAIN 320  // 5 full waves; threads with d>=300 are masked

// Build segment start offsets from sorted segment_ids.
// seg_start[b] = first index j with segment_ids[j] >= b ; seg_start[nseg] = total.
// Covers every b in [0, nseg] even for empty segments (d_ws is re-poisoned each call,
// so we must write all entries every launch — we do).
__global__ void seg_bounds_kernel(const int* __restrict__ seg,
                                  int* __restrict__ seg_start,
                                  int total, int nseg) {
    int i = blockIdx.x * blockDim.x + threadIdx.x;
    if (i >= total) return;
    int s = seg[i];
    int prev = (i == 0) ? -1 : seg[i - 1];
    for (int b = prev + 1; b <= s; ++b) seg_start[b] = i;
    if (i == total - 1) {
        for (int b = s + 1; b <= nseg; ++b) seg_start[b] = total;
    }
}

// One block per output row b. Thread d accumulates dim d across the row's
// contiguous ngram slice [seg_start[b], seg_start[b+1]).
__global__ __launch_bounds__(BLOCK_MAIN) void fasttext_fwd(
    const int* __restrict__ center_ids,
    const int* __restrict__ ngram_idx,
    const int* __restrict__ seg_start,
    const float* __restrict__ W_in,
    const float* __restrict__ W_sub,
    float* __restrict__ out)
{
    const int b = blockIdx.x;
    const int d = threadIdx.x;
    const bool active = d < D;

    const int start = seg_start[b];
    const int end   = seg_start[b + 1];

    float acc = 0.0f;
    if (active) acc = W_in[(size_t)center_ids[b] * D + d];

    int j = start;
    // Unroll x4: 4 independent gather rows in flight per iteration.
    for (; j + 4 <= end; j += 4) {
        int i0 = ngram_idx[j + 0];
        int i1 = ngram_idx[j + 1];
        int i2 = ngram_idx[j + 2];
        int i3 = ngram_idx[j + 3];
        if (active) {
            float v0 = W_sub[(size_t)i0 * D + d];
            float v1 = W_sub[(size_t)i1 * D + d];
            float v2 = W_sub[(size_t)i2 * D + d];
            float v3 = W_sub[(size_t)i3 * D + d];
            acc += v0; acc += v1; acc += v2; acc += v3;
        }
    }
    for (; j < end; ++j) {
        int i0 = ngram_idx[j];
        if (active) acc += W_sub[(size_t)i0 * D + d];
    }

    if (active) out[(size_t)b * D + d] = acc;
}

// Fallback if d_ws is too small: binary-search segment bounds per block.
__global__ __launch_bounds__(BLOCK_MAIN) void fasttext_fwd_bsearch(
    const int* __restrict__ center_ids,
    const int* __restrict__ ngram_idx,
    const int* __restrict__ seg,
    const float* __restrict__ W_in,
    const float* __restrict__ W_sub,
    float* __restrict__ out,
    int total)
{
    const int b = blockIdx.x;
    const int d = threadIdx.x;
    const bool active = d < D;

    // lower_bound(seg, b)
    int lo = 0, hi = total;
    while (lo < hi) { int mid = (lo + hi) >> 1; if (seg[mid] < b) lo = mid + 1; else hi = mid; }
    const int start = lo;
    hi = total;
    while (lo < hi) { int mid = (lo + hi) >> 1; if (seg[mid] < b + 1) lo = mid + 1; else hi = mid; }
    const int end = lo;

    float acc = 0.0f;
    if (active) acc = W_in[(size_t)center_ids[b] * D + d];

    int j = start;
    for (; j + 4 <= end; j += 4) {
        int i0 = ngram_idx[j + 0];
        int i1 = ngram_idx[j + 1];
        int i2 = ngram_idx[j + 2];
        int i3 = ngram_idx[j + 3];
        if (active) {
            float v0 = W_sub[(size_t)i0 * D + d];
            float v1 = W_sub[(size_t)i1 * D + d];
            float v2 = W_sub[(size_t)i2 * D + d];
            float v3 = W_sub[(size_t)i3 * D + d];
            acc += v0; acc += v1; acc += v2; acc += v3;
        }
    }
    for (; j < end; ++j) {
        int i0 = ngram_idx[j];
        if (active) acc += W_sub[(size_t)i0 * D + d];
    }

    if (active) out[(size_t)b * D + d] = acc;
}

extern "C" void kernel_launch(void* const* d_in, const int* in_sizes, int n_in,
                              void* d_out, int out_size, void* d_ws, size_t ws_size,
                              hipStream_t stream) {
    const int*   center_ids  = (const int*)d_in[0];   // (B,) int32
    const int*   ngram_idx   = (const int*)d_in[1];   // (TOTAL,) int32
    const int*   segment_ids = (const int*)d_in[2];   // (TOTAL,) int32, sorted
    const float* W_in        = (const float*)d_in[3]; // (VOCAB, D) f32
    const float* W_sub       = (const float*)d_in[4]; // (BUCKET, D) f32
    float*       out         = (float*)d_out;         // (B, D) f32

    const int nseg  = in_sizes[0];  // B
    const int total = in_sizes[1];  // TOTAL

    const size_t ws_needed = (size_t)(nseg + 1) * sizeof(int);
    if (ws_size >= ws_needed) {
        int* seg_start = (int*)d_ws;
        seg_bounds_kernel<<<(total + 255) / 256, 256, 0, stream>>>(
            segment_ids, seg_start, total, nseg);
        fasttext_fwd<<<nseg, BLOCK_MAIN, 0, stream>>>(
            center_ids, ngram_idx, seg_start, W_in, W_sub, out);
    } else {
        fasttext_fwd_bsearch<<<nseg, BLOCK_MAIN, 0, stream>>>(
            center_ids, ngram_idx, segment_ids, W_in, W_sub, out, total);
    }
}